// Round 13
// baseline (551.156 us; speedup 1.0000x reference)
//
#include <hip/hip_runtime.h>

typedef __attribute__((ext_vector_type(8))) __bf16 bf16x8;
typedef __attribute__((ext_vector_type(4))) float f32x4;

#define IMG 112
#define SHF 3

__device__ __forceinline__ ushort f2bf(float f) {
  return __builtin_bit_cast(unsigned short, static_cast<__bf16>(f));
}
__device__ __forceinline__ int d7(int n) { return (n * 9363) >> 16; }  // n/7 for n<=63

// ---------------- prep: bf16 weights (+q scale fold), biases, rpb+mask table ----------------
__global__ void prep_kernel(const float* __restrict__ Wq, const float* __restrict__ Wk,
                            const float* __restrict__ Wv, const float* __restrict__ Wp,
                            const float* __restrict__ bq, const float* __restrict__ bk,
                            const float* __restrict__ bv, const float* __restrict__ bp,
                            const float* __restrict__ tbl,
                            ushort* __restrict__ wW, float* __restrict__ wB,
                            float* __restrict__ wRM) {
  int t = blockIdx.x * 256 + threadIdx.x;
  const float SC = 0.17677669529663687f;  // 32^-0.5
  if (t < 65536) {
    int m = t >> 14, e = t & 16383;
    const float* W = (m == 0) ? Wq : (m == 1) ? Wk : (m == 2) ? Wv : Wp;
    float v = W[e];
    if (m == 0) v *= SC;
    wW[t] = f2bf(v);
  } else if (t < 66048) {
    int t2 = t - 65536;
    int m = t2 >> 7, e = t2 & 127;
    const float* B = (m == 0) ? bq : (m == 1) ? bk : (m == 2) ? bv : bp;
    float v = B[e];
    if (m == 0) v *= SC;
    wB[t2] = v;
  } else if (t < 131584) {
    int t3 = t - 66048;  // [0, 65536)
    int cls = t3 >> 14;
    int r = t3 & 16383;
    int h = r >> 12;
    int rr = r & 4095;
    int qt = rr >> 6, kt = rr & 63;
    float v;
    if (qt >= 49) v = 0.0f;
    else if (kt >= 49) v = -1e30f;
    else {
      int rq = qt / 7, cq = qt % 7, rk = kt / 7, ck = kt % 7;
      v = tbl[((rq - rk + 6) * 13 + (cq - ck + 6)) * 4 + h];
      int eH = (cls >> 1) & 1, eW = cls & 1;
      int ridq = (eH ? (rq < 4 ? 3 : 6) : 0) + (eW ? (cq < 4 ? 1 : 2) : 0);
      int ridk = (eH ? (rk < 4 ? 3 : 6) : 0) + (eW ? (ck < 4 ? 1 : 2) : 0);
      if (ridq != ridk) v -= 100.0f;
    }
    wRM[t3] = v;
  }
}

// ======================= split path kernel 1: gather + QKV GEMMs =======================
// qg/km: [win][49][128] bf16;  vg: [win][128][64] bf16 (V transposed, row stride 64).
__global__ __launch_bounds__(512, 4) void qkv_kernel(
    const float* __restrict__ X, const ushort* __restrict__ wW,
    const float* __restrict__ wB,
    ushort* __restrict__ qg, ushort* __restrict__ km, ushort* __restrict__ vg) {
  __shared__ ushort lds[6664];  // x_s[49][136]
  const int tid = threadIdx.x;
  const int wv = tid >> 6;
  const int lane = tid & 63;
  const int lr = lane & 15;
  const int kg = lane >> 4;

  const int blk = blockIdx.x;   // = window id global
  const int b = blk >> 8;
  const int wid = blk & 255;
  const int wi = wid >> 4, wj = wid & 15;
  const size_t gBase = (size_t)b * (IMG * IMG * 128);

  // Phase A: gather rolled window (4 independent chains)
  {
    float4 va[4]; int rowa[4], q4a[4]; bool ok[4];
#pragma unroll
    for (int i = 0; i < 4; ++i) {
      int idx = tid + i * 512;
      ok[i] = idx < 49 * 32;
      int row = idx >> 5, q4 = idx & 31;
      rowa[i] = row; q4a[i] = q4;
      if (ok[i]) {
        int r = d7(row), c = row - r * 7;
        int gh = wi * 7 + r + SHF; if (gh >= IMG) gh -= IMG;
        int gw = wj * 7 + c + SHF; if (gw >= IMG) gw -= IMG;
        va[i] = reinterpret_cast<const float4*>(X + gBase + ((size_t)gh * IMG + gw) * 128)[q4];
      }
    }
#pragma unroll
    for (int i = 0; i < 4; ++i) {
      if (ok[i]) {
        ushort4 h4 = { f2bf(va[i].x), f2bf(va[i].y), f2bf(va[i].z), f2bf(va[i].w) };
        *reinterpret_cast<ushort4*>(&lds[rowa[i] * 136 + q4a[i] * 4]) = h4;
      }
    }
  }
  __syncthreads();

  const int wc = wv & 3, wt = wv >> 2;
  const int c0 = wc * 32, t0 = wt * 32;

  // q, k: swapped GEMMs D[ch][tok] -> [tok][ch] vector writes
#pragma unroll
  for (int pj = 0; pj < 2; ++pj) {
    const ushort* W = wW + pj * 16384;
    bf16x8 aw[4][2], bx[4][2];
#pragma unroll
    for (int kk = 0; kk < 4; ++kk)
#pragma unroll
      for (int mt = 0; mt < 2; ++mt)
        aw[kk][mt] = *reinterpret_cast<const bf16x8*>(&W[(c0 + mt * 16 + lr) * 128 + kk * 32 + kg * 8]);
#pragma unroll
    for (int kk = 0; kk < 4; ++kk)
#pragma unroll
      for (int nt = 0; nt < 2; ++nt) {
        int tok = t0 + nt * 16 + lr; if (tok > 48) tok = 48;
        bx[kk][nt] = *reinterpret_cast<const bf16x8*>(&lds[tok * 136 + kk * 32 + kg * 8]);
      }
    f32x4 acc[2][2] = {};
#pragma unroll
    for (int kk = 0; kk < 4; ++kk)
#pragma unroll
      for (int mt = 0; mt < 2; ++mt)
#pragma unroll
        for (int nt = 0; nt < 2; ++nt)
          acc[mt][nt] = __builtin_amdgcn_mfma_f32_16x16x32_bf16(aw[kk][mt], bx[kk][nt], acc[mt][nt], 0, 0, 0);
    ushort* dst = ((pj == 0) ? qg : km) + (size_t)blk * 6272;
#pragma unroll
    for (int mt = 0; mt < 2; ++mt) {
      float4 b4 = *reinterpret_cast<const float4*>(&wB[pj * 128 + c0 + mt * 16 + kg * 4]);
#pragma unroll
      for (int nt = 0; nt < 2; ++nt) {
        int tok = t0 + nt * 16 + lr;
        if (tok < 49) {
          ushort4 h4 = { f2bf(acc[mt][nt][0] + b4.x), f2bf(acc[mt][nt][1] + b4.y),
                         f2bf(acc[mt][nt][2] + b4.z), f2bf(acc[mt][nt][3] + b4.w) };
          *reinterpret_cast<ushort4*>(&dst[tok * 128 + c0 + mt * 16 + kg * 4]) = h4;
        }
      }
    }
  }
  // v: D[tok][ch] -> vT[ch][tok] vector writes (row stride 64, covers tok 0..63)
  {
    const ushort* W = wW + 2 * 16384;
    bf16x8 bw[4][2], ax[4][2];
#pragma unroll
    for (int kk = 0; kk < 4; ++kk)
#pragma unroll
      for (int nt = 0; nt < 2; ++nt)
        bw[kk][nt] = *reinterpret_cast<const bf16x8*>(&W[(c0 + nt * 16 + lr) * 128 + kk * 32 + kg * 8]);
#pragma unroll
    for (int kk = 0; kk < 4; ++kk)
#pragma unroll
      for (int mt = 0; mt < 2; ++mt) {
        int tok = t0 + mt * 16 + lr; if (tok > 48) tok = 48;
        ax[kk][mt] = *reinterpret_cast<const bf16x8*>(&lds[tok * 136 + kk * 32 + kg * 8]);
      }
    f32x4 acc[2][2] = {};
#pragma unroll
    for (int kk = 0; kk < 4; ++kk)
#pragma unroll
      for (int mt = 0; mt < 2; ++mt)
#pragma unroll
        for (int nt = 0; nt < 2; ++nt)
          acc[mt][nt] = __builtin_amdgcn_mfma_f32_16x16x32_bf16(ax[kk][mt], bw[kk][nt], acc[mt][nt], 0, 0, 0);
    ushort* dst = vg + (size_t)blk * 8192;
#pragma unroll
    for (int nt = 0; nt < 2; ++nt) {
      float bias = wB[256 + c0 + nt * 16 + lr];
#pragma unroll
      for (int mt = 0; mt < 2; ++mt) {
        ushort4 h4 = { f2bf(acc[mt][nt][0] + bias), f2bf(acc[mt][nt][1] + bias),
                       f2bf(acc[mt][nt][2] + bias), f2bf(acc[mt][nt][3] + bias) };
        *reinterpret_cast<ushort4*>(&dst[(c0 + nt * 16 + lr) * 64 + t0 + mt * 16 + kg * 4]) = h4;
      }
    }
  }
}

// ======================= split path kernel 2: attention + proj + scatter =======================
// LDS: p_s [0,9216) = [2][64][72];  o_s [9216, 15880) = [49][136].
#define OS2 9216
__global__ __launch_bounds__(512, 4) void attn_kernel(
    const ushort* __restrict__ qg, const ushort* __restrict__ km,
    const ushort* __restrict__ vg, const ushort* __restrict__ wW,
    const float* __restrict__ wB, const float* __restrict__ wRM,
    float* __restrict__ out) {
  __shared__ ushort lds[15880];
  const int tid = threadIdx.x;
  const int wv = tid >> 6;
  const int lane = tid & 63;
  const int lr = lane & 15;
  const int kg = lane >> 4;

  const int blk = blockIdx.x;
  const int b = blk >> 8;
  const int wid = blk & 255;
  const int wi = wid >> 4, wj = wid & 15;
  const size_t gBase = (size_t)b * (IMG * IMG * 128);

  const int wc = wv & 3, wt = wv >> 2;
  const int c0 = wc * 32, t0 = wt * 32;
  const int hloc = wv >> 2, mq = wv & 3;
  const int qt = mq * 16 + lr;
  const int qtc = qt > 48 ? 48 : qt;
  const int cls = ((wi == 15) ? 2 : 0) + ((wj == 15) ? 1 : 0);

  const ushort* qw = qg + (size_t)blk * 6272;
  const ushort* kw = km + (size_t)blk * 6272;
  const ushort* vw = vg + (size_t)blk * 8192;

  f32x4 oacc[2][2] = {};
#pragma unroll
  for (int pass = 0; pass < 2; ++pass) {
    const int h = pass * 2 + hloc;
    // hoist all loads: rpb (L2), Q/K/V (global, L3-hot)
    const float* rp = wRM + (((size_t)cls * 4 + h) * 64 + qt) * 64;
    float4 r4[4];
#pragma unroll
    for (int at = 0; at < 4; ++at)
      r4[at] = *reinterpret_cast<const float4*>(&rp[at * 16 + kg * 4]);
    bf16x8 bq = *reinterpret_cast<const bf16x8*>(&qw[qtc * 128 + h * 32 + kg * 8]);
    bf16x8 ak[4];
#pragma unroll
    for (int at = 0; at < 4; ++at) {
      int kt = at * 16 + lr; if (kt > 48) kt = 48;
      ak[at] = *reinterpret_cast<const bf16x8*>(&kw[kt * 128 + h * 32 + kg * 8]);
    }
    bf16x8 av[2][2];
#pragma unroll
    for (int kk = 0; kk < 2; ++kk)
#pragma unroll
      for (int mt = 0; mt < 2; ++mt)
        av[kk][mt] = *reinterpret_cast<const bf16x8*>(&vw[(h * 32 + mt * 16 + lr) * 64 + kk * 32 + kg * 8]);
    // S^T = K Q^T
    f32x4 s[4] = {};
#pragma unroll
    for (int at = 0; at < 4; ++at)
      s[at] = __builtin_amdgcn_mfma_f32_16x16x32_bf16(ak[at], bq, s[at], 0, 0, 0);
    // softmax over kt
    float mx = -3.0e38f;
#pragma unroll
    for (int at = 0; at < 4; ++at) {
      s[at][0] += r4[at].x; s[at][1] += r4[at].y; s[at][2] += r4[at].z; s[at][3] += r4[at].w;
      mx = fmaxf(mx, fmaxf(fmaxf(s[at][0], s[at][1]), fmaxf(s[at][2], s[at][3])));
    }
    mx = fmaxf(mx, __shfl_xor(mx, 16));
    mx = fmaxf(mx, __shfl_xor(mx, 32));
    float sum = 0.0f;
#pragma unroll
    for (int at = 0; at < 4; ++at) {
#pragma unroll
      for (int i = 0; i < 4; ++i) {
        float e = __expf(s[at][i] - mx);
        s[at][i] = e; sum += e;
      }
    }
    sum += __shfl_xor(sum, 16);
    sum += __shfl_xor(sum, 32);
    float inv = 1.0f / sum;
    const int pb = hloc * 4608 + qt * 72;
#pragma unroll
    for (int at = 0; at < 4; ++at) {
      ushort4 p4 = { f2bf(s[at][0] * inv), f2bf(s[at][1] * inv),
                     f2bf(s[at][2] * inv), f2bf(s[at][3] * inv) };
      *reinterpret_cast<ushort4*>(&lds[pb + at * 16 + kg * 4]) = p4;
    }
    // O^T = V^T P^T (V in regs; P via same-wave LDS round trip)
#pragma unroll
    for (int kk = 0; kk < 2; ++kk) {
      bf16x8 bp = *reinterpret_cast<const bf16x8*>(&lds[pb + kk * 32 + kg * 8]);
#pragma unroll
      for (int mt = 0; mt < 2; ++mt)
        oacc[pass][mt] = __builtin_amdgcn_mfma_f32_16x16x32_bf16(av[kk][mt], bp, oacc[pass][mt], 0, 0, 0);
    }
  }

  // O -> o_s (wave-private rows; no barrier needed before)
#pragma unroll
  for (int pass = 0; pass < 2; ++pass) {
#pragma unroll
    for (int mt = 0; mt < 2; ++mt) {
      if (qt < 49) {
        ushort4 h4 = { f2bf(oacc[pass][mt][0]), f2bf(oacc[pass][mt][1]),
                       f2bf(oacc[pass][mt][2]), f2bf(oacc[pass][mt][3]) };
        *reinterpret_cast<ushort4*>(&lds[OS2 + qt * 136 + (pass * 2 + hloc) * 32 + mt * 16 + kg * 4]) = h4;
      }
    }
  }
  // proj weights issued before the barrier
  bf16x8 eaw[4][2];
  {
    const ushort* W = wW + 3 * 16384;
#pragma unroll
    for (int kk = 0; kk < 4; ++kk)
#pragma unroll
      for (int mt = 0; mt < 2; ++mt)
        eaw[kk][mt] = *reinterpret_cast<const bf16x8*>(&W[(c0 + mt * 16 + lr) * 128 + kk * 32 + kg * 8]);
  }
  __syncthreads();

  // output projection + scatter
  {
    bf16x8 bo[4][2];
#pragma unroll
    for (int kk = 0; kk < 4; ++kk)
#pragma unroll
      for (int nt = 0; nt < 2; ++nt) {
        int tok = t0 + nt * 16 + lr; if (tok > 48) tok = 48;
        bo[kk][nt] = *reinterpret_cast<const bf16x8*>(&lds[OS2 + tok * 136 + kk * 32 + kg * 8]);
      }
    f32x4 acc[2][2] = {};
#pragma unroll
    for (int kk = 0; kk < 4; ++kk)
#pragma unroll
      for (int mt = 0; mt < 2; ++mt)
#pragma unroll
        for (int nt = 0; nt < 2; ++nt)
          acc[mt][nt] = __builtin_amdgcn_mfma_f32_16x16x32_bf16(eaw[kk][mt], bo[kk][nt], acc[mt][nt], 0, 0, 0);
#pragma unroll
    for (int mt = 0; mt < 2; ++mt) {
      float4 b4 = *reinterpret_cast<const float4*>(&wB[384 + c0 + mt * 16 + kg * 4]);
#pragma unroll
      for (int nt = 0; nt < 2; ++nt) {
        int tok = t0 + nt * 16 + lr;
        if (tok < 49) {
          int r = d7(tok), c = tok - r * 7;
          int gh = wi * 7 + r + SHF; if (gh >= IMG) gh -= IMG;
          int gw = wj * 7 + c + SHF; if (gw >= IMG) gw -= IMG;
          float4 o4 = { acc[mt][nt][0] + b4.x, acc[mt][nt][1] + b4.y,
                        acc[mt][nt][2] + b4.z, acc[mt][nt][3] + b4.w };
          *reinterpret_cast<float4*>(out + gBase + ((size_t)gh * IMG + gw) * 128 + c0 + mt * 16 + kg * 4) = o4;
        }
      }
    }
  }
}

// ======================= fallback: R11 fused kernel (verbatim) =======================
#define QS 9216
#define KS 15880
#define VT 22544
__global__ __launch_bounds__(512, 4) void swin_kernel(
    const float* __restrict__ X, const ushort* __restrict__ wW,
    const float* __restrict__ wB, const float* __restrict__ wRM,
    float* __restrict__ out) {
  __shared__ ushort lds[31760];
  const int tid = threadIdx.x;
  const int wv = tid >> 6;
  const int lane = tid & 63;
  const int lr = lane & 15;
  const int kg = lane >> 4;
  const int blk = blockIdx.x;
  const int b = blk >> 8;
  const int wid = blk & 255;
  const int wi = wid >> 4, wj = wid & 15;
  const size_t gBase = (size_t)b * (IMG * IMG * 128);
  {
    float4 va[4]; int rowa[4], q4a[4]; bool ok[4];
#pragma unroll
    for (int i = 0; i < 4; ++i) {
      int idx = tid + i * 512;
      ok[i] = idx < 49 * 32;
      int row = idx >> 5, q4 = idx & 31;
      rowa[i] = row; q4a[i] = q4;
      if (ok[i]) {
        int r = d7(row), c = row - r * 7;
        int gh = wi * 7 + r + SHF; if (gh >= IMG) gh -= IMG;
        int gw = wj * 7 + c + SHF; if (gw >= IMG) gw -= IMG;
        va[i] = reinterpret_cast<const float4*>(X + gBase + ((size_t)gh * IMG + gw) * 128)[q4];
      }
    }
#pragma unroll
    for (int i = 0; i < 4; ++i) {
      if (ok[i]) {
        ushort4 h4 = { f2bf(va[i].x), f2bf(va[i].y), f2bf(va[i].z), f2bf(va[i].w) };
        *reinterpret_cast<ushort4*>(&lds[rowa[i] * 136 + q4a[i] * 4]) = h4;
      }
    }
  }
  __syncthreads();
  const int wc = wv & 3, wt = wv >> 2;
  const int c0 = wc * 32, t0 = wt * 32;
  const int hloc = wv >> 2, mq = wv & 3;
  const int qt = mq * 16 + lr;
  const int qtc = qt > 48 ? 48 : qt;
#pragma unroll
  for (int pj = 0; pj < 2; ++pj) {
    const ushort* W = wW + pj * 16384;
    bf16x8 aw[4][2], bx[4][2];
#pragma unroll
    for (int kk = 0; kk < 4; ++kk)
#pragma unroll
      for (int mt = 0; mt < 2; ++mt)
        aw[kk][mt] = *reinterpret_cast<const bf16x8*>(&W[(c0 + mt * 16 + lr) * 128 + kk * 32 + kg * 8]);
#pragma unroll
    for (int kk = 0; kk < 4; ++kk)
#pragma unroll
      for (int nt = 0; nt < 2; ++nt) {
        int tok = t0 + nt * 16 + lr; if (tok > 48) tok = 48;
        bx[kk][nt] = *reinterpret_cast<const bf16x8*>(&lds[tok * 136 + kk * 32 + kg * 8]);
      }
    f32x4 acc[2][2] = {};
#pragma unroll
    for (int kk = 0; kk < 4; ++kk)
#pragma unroll
      for (int mt = 0; mt < 2; ++mt)
#pragma unroll
        for (int nt = 0; nt < 2; ++nt)
          acc[mt][nt] = __builtin_amdgcn_mfma_f32_16x16x32_bf16(aw[kk][mt], bx[kk][nt], acc[mt][nt], 0, 0, 0);
    const int sb = (pj == 0) ? QS : KS;
#pragma unroll
    for (int mt = 0; mt < 2; ++mt) {
      float4 b4 = *reinterpret_cast<const float4*>(&wB[pj * 128 + c0 + mt * 16 + kg * 4]);
#pragma unroll
      for (int nt = 0; nt < 2; ++nt) {
        int tok = t0 + nt * 16 + lr;
        if (tok < 49) {
          ushort4 h4 = { f2bf(acc[mt][nt][0] + b4.x), f2bf(acc[mt][nt][1] + b4.y),
                         f2bf(acc[mt][nt][2] + b4.z), f2bf(acc[mt][nt][3] + b4.w) };
          *reinterpret_cast<ushort4*>(&lds[sb + tok * 136 + c0 + mt * 16 + kg * 4]) = h4;
        }
      }
    }
  }
  {
    const ushort* W = wW + 2 * 16384;
    bf16x8 bw[4][2], ax[4][2];
#pragma unroll
    for (int kk = 0; kk < 4; ++kk)
#pragma unroll
      for (int nt = 0; nt < 2; ++nt)
        bw[kk][nt] = *reinterpret_cast<const bf16x8*>(&W[(c0 + nt * 16 + lr) * 128 + kk * 32 + kg * 8]);
#pragma unroll
    for (int kk = 0; kk < 4; ++kk)
#pragma unroll
      for (int mt = 0; mt < 2; ++mt) {
        int tok = t0 + mt * 16 + lr; if (tok > 48) tok = 48;
        ax[kk][mt] = *reinterpret_cast<const bf16x8*>(&lds[tok * 136 + kk * 32 + kg * 8]);
      }
    f32x4 acc[2][2] = {};
#pragma unroll
    for (int kk = 0; kk < 4; ++kk)
#pragma unroll
      for (int mt = 0; mt < 2; ++mt)
#pragma unroll
        for (int nt = 0; nt < 2; ++nt)
          acc[mt][nt] = __builtin_amdgcn_mfma_f32_16x16x32_bf16(ax[kk][mt], bw[kk][nt], acc[mt][nt], 0, 0, 0);
#pragma unroll
    for (int nt = 0; nt < 2; ++nt) {
      float bias = wB[256 + c0 + nt * 16 + lr];
#pragma unroll
      for (int mt = 0; mt < 2; ++mt) {
        ushort4 h4 = { f2bf(acc[mt][nt][0] + bias), f2bf(acc[mt][nt][1] + bias),
                       f2bf(acc[mt][nt][2] + bias), f2bf(acc[mt][nt][3] + bias) };
        *reinterpret_cast<ushort4*>(&lds[VT + (c0 + nt * 16 + lr) * 72 + t0 + mt * 16 + kg * 4]) = h4;
      }
    }
  }
  __syncthreads();
  const int cls = ((wi == 15) ? 2 : 0) + ((wj == 15) ? 1 : 0);
  f32x4 oacc[2][2] = {};
#pragma unroll
  for (int pass = 0; pass < 2; ++pass) {
    const int h = pass * 2 + hloc;
    const float* rp = wRM + (((size_t)cls * 4 + h) * 64 + qt) * 64;
    float4 r4[4];
#pragma unroll
    for (int at = 0; at < 4; ++at)
      r4[at] = *reinterpret_cast<const float4*>(&rp[at * 16 + kg * 4]);
    bf16x8 bq = *reinterpret_cast<const bf16x8*>(&lds[QS + qtc * 136 + h * 32 + kg * 8]);
    bf16x8 ak[4];
#pragma unroll
    for (int at = 0; at < 4; ++at) {
      int kt = at * 16 + lr; if (kt > 48) kt = 48;
      ak[at] = *reinterpret_cast<const bf16x8*>(&lds[KS + kt * 136 + h * 32 + kg * 8]);
    }
    bf16x8 av[2][2];
#pragma unroll
    for (int kk = 0; kk < 2; ++kk)
#pragma unroll
      for (int mt = 0; mt < 2; ++mt)
        av[kk][mt] = *reinterpret_cast<const bf16x8*>(&lds[VT + (h * 32 + mt * 16 + lr) * 72 + kk * 32 + kg * 8]);
    f32x4 s[4] = {};
#pragma unroll
    for (int at = 0; at < 4; ++at)
      s[at] = __builtin_amdgcn_mfma_f32_16x16x32_bf16(ak[at], bq, s[at], 0, 0, 0);
    float mx = -3.0e38f;
#pragma unroll
    for (int at = 0; at < 4; ++at) {
      s[at][0] += r4[at].x; s[at][1] += r4[at].y; s[at][2] += r4[at].z; s[at][3] += r4[at].w;
      mx = fmaxf(mx, fmaxf(fmaxf(s[at][0], s[at][1]), fmaxf(s[at][2], s[at][3])));
    }
    mx = fmaxf(mx, __shfl_xor(mx, 16));
    mx = fmaxf(mx, __shfl_xor(mx, 32));
    float sum = 0.0f;
#pragma unroll
    for (int at = 0; at < 4; ++at) {
#pragma unroll
      for (int i = 0; i < 4; ++i) {
        float e = __expf(s[at][i] - mx);
        s[at][i] = e; sum += e;
      }
    }
    sum += __shfl_xor(sum, 16);
    sum += __shfl_xor(sum, 32);
    float inv = 1.0f / sum;
    const int pb = hloc * 4608 + qt * 72;
#pragma unroll
    for (int at = 0; at < 4; ++at) {
      ushort4 p4 = { f2bf(s[at][0] * inv), f2bf(s[at][1] * inv),
                     f2bf(s[at][2] * inv), f2bf(s[at][3] * inv) };
      *reinterpret_cast<ushort4*>(&lds[pb + at * 16 + kg * 4]) = p4;
    }
#pragma unroll
    for (int kk = 0; kk < 2; ++kk) {
      bf16x8 bp = *reinterpret_cast<const bf16x8*>(&lds[pb + kk * 32 + kg * 8]);
#pragma unroll
      for (int mt = 0; mt < 2; ++mt)
        oacc[pass][mt] = __builtin_amdgcn_mfma_f32_16x16x32_bf16(av[kk][mt], bp, oacc[pass][mt], 0, 0, 0);
    }
  }
#pragma unroll
  for (int pass = 0; pass < 2; ++pass) {
#pragma unroll
    for (int mt = 0; mt < 2; ++mt) {
      if (qt < 49) {
        ushort4 h4 = { f2bf(oacc[pass][mt][0]), f2bf(oacc[pass][mt][1]),
                       f2bf(oacc[pass][mt][2]), f2bf(oacc[pass][mt][3]) };
        *reinterpret_cast<ushort4*>(&lds[QS + qt * 136 + (pass * 2 + hloc) * 32 + mt * 16 + kg * 4]) = h4;
      }
    }
  }
  bf16x8 eaw[4][2];
  {
    const ushort* W = wW + 3 * 16384;
#pragma unroll
    for (int kk = 0; kk < 4; ++kk)
#pragma unroll
      for (int mt = 0; mt < 2; ++mt)
        eaw[kk][mt] = *reinterpret_cast<const bf16x8*>(&W[(c0 + mt * 16 + lr) * 128 + kk * 32 + kg * 8]);
  }
  __syncthreads();
  {
    bf16x8 bo[4][2];
#pragma unroll
    for (int kk = 0; kk < 4; ++kk)
#pragma unroll
      for (int nt = 0; nt < 2; ++nt) {
        int tok = t0 + nt * 16 + lr; if (tok > 48) tok = 48;
        bo[kk][nt] = *reinterpret_cast<const bf16x8*>(&lds[QS + tok * 136 + kk * 32 + kg * 8]);
      }
    f32x4 acc[2][2] = {};
#pragma unroll
    for (int kk = 0; kk < 4; ++kk)
#pragma unroll
      for (int mt = 0; mt < 2; ++mt)
#pragma unroll
        for (int nt = 0; nt < 2; ++nt)
          acc[mt][nt] = __builtin_amdgcn_mfma_f32_16x16x32_bf16(eaw[kk][mt], bo[kk][nt], acc[mt][nt], 0, 0, 0);
#pragma unroll
    for (int mt = 0; mt < 2; ++mt) {
      float4 b4 = *reinterpret_cast<const float4*>(&wB[384 + c0 + mt * 16 + kg * 4]);
#pragma unroll
      for (int nt = 0; nt < 2; ++nt) {
        int tok = t0 + nt * 16 + lr;
        if (tok < 49) {
          int r = d7(tok), c = tok - r * 7;
          int gh = wi * 7 + r + SHF; if (gh >= IMG) gh -= IMG;
          int gw = wj * 7 + c + SHF; if (gw >= IMG) gw -= IMG;
          float4 o4 = { acc[mt][nt][0] + b4.x, acc[mt][nt][1] + b4.y,
                        acc[mt][nt][2] + b4.z, acc[mt][nt][3] + b4.w };
          *reinterpret_cast<float4*>(out + gBase + ((size_t)gh * IMG + gw) * 128 + c0 + mt * 16 + kg * 4) = o4;
        }
      }
    }
  }
}

extern "C" void kernel_launch(void* const* d_in, const int* in_sizes, int n_in,
                              void* d_out, int out_size, void* d_ws, size_t ws_size,
                              hipStream_t stream) {
  const float* X = (const float*)d_in[0];
  const float* Wq = (const float*)d_in[3];
  const float* Wk = (const float*)d_in[4];
  const float* Wv = (const float*)d_in[5];
  const float* Wp = (const float*)d_in[6];
  const float* bq = (const float*)d_in[7];
  const float* bk = (const float*)d_in[8];
  const float* bv = (const float*)d_in[9];
  const float* bp = (const float*)d_in[10];
  const float* tbl = (const float*)d_in[11];

  ushort* wW = (ushort*)d_ws;                             // 131072 B
  float* wB = (float*)((char*)d_ws + 131072);             // 2048 B
  float* wRM = (float*)((char*)d_ws + 131072 + 2048);     // 262144 B
  const size_t base = 395264;

  const size_t qkBytes = (size_t)8192 * 6272 * 2;         // 102,760,448 each
  const size_t vBytes = (size_t)8192 * 8192 * 2;          // 134,217,728
  const size_t need = base + 2 * qkBytes + vBytes + 1024;

  prep_kernel<<<dim3(514), dim3(256), 0, stream>>>(Wq, Wk, Wv, Wp, bq, bk, bv, bp, tbl, wW, wB, wRM);

  if (ws_size >= need) {
    ushort* qg = (ushort*)((char*)d_ws + base);
    ushort* km = (ushort*)((char*)d_ws + base + qkBytes);
    ushort* vg = (ushort*)((char*)d_ws + base + 2 * qkBytes);
    qkv_kernel<<<dim3(8192), dim3(512), 0, stream>>>(X, wW, wB, qg, km, vg);
    attn_kernel<<<dim3(8192), dim3(512), 0, stream>>>(qg, km, vg, wW, wB, wRM, (float*)d_out);
  } else {
    swin_kernel<<<dim3(8192), dim3(512), 0, stream>>>(X, wW, wB, wRM, (float*)d_out);
  }
}

// Round 14
// 282.201 us; speedup vs baseline: 1.9531x; 1.9531x over previous
//
#include <hip/hip_runtime.h>

typedef __attribute__((ext_vector_type(8))) __bf16 bf16x8;
typedef __attribute__((ext_vector_type(4))) float f32x4;

#define IMG 112
#define SHF 3

__device__ __forceinline__ ushort f2bf(float f) {
  return __builtin_bit_cast(unsigned short, static_cast<__bf16>(f));
}
__device__ __forceinline__ uint pk2(float lo, float hi) {
  return (uint)f2bf(lo) | ((uint)f2bf(hi) << 16);
}
__device__ __forceinline__ int d7(int n) { return (n * 9363) >> 16; }  // n/7 for n<=63

// Zero-padded K=16 embedding (verified R10): D-frag regs {v0,v1,v2,v3} at k'=8kg+{0..3};
// both MFMA operands packed identically -> contraction over the 16 source rows.
__device__ __forceinline__ bf16x8 padd(const f32x4 d) {
  union { uint4 u; bf16x8 v; } r;
  r.u = uint4{ pk2(d[0], d[1]), pk2(d[2], d[3]), 0u, 0u };
  return r.v;
}
__device__ __forceinline__ bf16x8 paddb(const f32x4 d, const float4 b) {
  union { uint4 u; bf16x8 v; } r;
  r.u = uint4{ pk2(d[0] + b.x, d[1] + b.y), pk2(d[2] + b.z, d[3] + b.w), 0u, 0u };
  return r.v;
}

// ---------------- prep: bf16 weights (+q scale fold), biases, rpb+mask table ----------------
// wRM[cls][h][64 qt][64 kt]: rpb + (-100 shift mask) + (-1e30 for kt>=49 pad); 0 for qt>=49.
__global__ void prep_kernel(const float* __restrict__ Wq, const float* __restrict__ Wk,
                            const float* __restrict__ Wv, const float* __restrict__ Wp,
                            const float* __restrict__ bq, const float* __restrict__ bk,
                            const float* __restrict__ bv, const float* __restrict__ bp,
                            const float* __restrict__ tbl,
                            ushort* __restrict__ wW, float* __restrict__ wB,
                            float* __restrict__ wRM) {
  int t = blockIdx.x * 256 + threadIdx.x;
  const float SC = 0.17677669529663687f;  // 32^-0.5
  if (t < 65536) {
    int m = t >> 14, e = t & 16383;
    const float* W = (m == 0) ? Wq : (m == 1) ? Wk : (m == 2) ? Wv : Wp;
    float v = W[e];
    if (m == 0) v *= SC;
    wW[t] = f2bf(v);
  } else if (t < 66048) {
    int t2 = t - 65536;
    int m = t2 >> 7, e = t2 & 127;
    const float* B = (m == 0) ? bq : (m == 1) ? bk : (m == 2) ? bv : bp;
    float v = B[e];
    if (m == 0) v *= SC;
    wB[t2] = v;
  } else if (t < 131584) {
    int t3 = t - 66048;  // [0, 65536)
    int cls = t3 >> 14;
    int r = t3 & 16383;
    int h = r >> 12;
    int rr = r & 4095;
    int qt = rr >> 6, kt = rr & 63;
    float v;
    if (qt >= 49) v = 0.0f;
    else if (kt >= 49) v = -1e30f;
    else {
      int rq = qt / 7, cq = qt % 7, rk = kt / 7, ck = kt % 7;
      v = tbl[((rq - rk + 6) * 13 + (cq - ck + 6)) * 4 + h];
      int eH = (cls >> 1) & 1, eW = cls & 1;
      int ridq = (eH ? (rq < 4 ? 3 : 6) : 0) + (eW ? (cq < 4 ? 1 : 2) : 0);
      int ridk = (eH ? (rk < 4 ? 3 : 6) : 0) + (eW ? (ck < 4 ? 1 : 2) : 0);
      if (ridq != ridk) v -= 100.0f;
    }
    wRM[t3] = v;
  }
}

// LDS (ushort units): x_s [0, 6664) = [49][136];  o_s [6664, 13328) = [49][136].
#define OS 6664

// Block = 256 threads = 4 waves; wave wv = head h, end-to-end in registers.
__global__ __launch_bounds__(256, 2) void swin_kernel(
    const float* __restrict__ X, const ushort* __restrict__ wW,
    const float* __restrict__ wB, const float* __restrict__ wRM,
    float* __restrict__ out) {
  __shared__ ushort lds[13328];
  const int tid = threadIdx.x;
  const int wv = tid >> 6;  // 0..3 = head
  const int lane = tid & 63;
  const int lr = lane & 15;
  const int kg = lane >> 4;

  const int blk = blockIdx.x;
  const int b = blk >> 8;
  const int wid = blk & 255;
  const int wi = wid >> 4, wj = wid & 15;
  const size_t gBase = (size_t)b * (IMG * IMG * 128);
  const int h = wv;

  // ---------------- Phase A: gather rolled window (hoisted chains) ----------------
  {
    float4 va[7]; int rowa[7], q4a[7]; bool ok[7];
#pragma unroll
    for (int i = 0; i < 7; ++i) {
      int idx = tid + i * 256;
      ok[i] = idx < 49 * 32;
      int row = idx >> 5, q4 = idx & 31;
      rowa[i] = row; q4a[i] = q4;
      if (ok[i]) {
        int r = d7(row), c = row - r * 7;
        int gh = wi * 7 + r + SHF; if (gh >= IMG) gh -= IMG;
        int gw = wj * 7 + c + SHF; if (gw >= IMG) gw -= IMG;
        va[i] = reinterpret_cast<const float4*>(X + gBase + ((size_t)gh * IMG + gw) * 128)[q4];
      }
    }
#pragma unroll
    for (int i = 0; i < 7; ++i) {
      if (ok[i]) {
        ushort4 h4 = { f2bf(va[i].x), f2bf(va[i].y), f2bf(va[i].z), f2bf(va[i].w) };
        *reinterpret_cast<ushort4*>(&lds[rowa[i] * 136 + q4a[i] * 4]) = h4;
      }
    }
  }
  __syncthreads();  // barrier 1

  // ---------------- x fragments (shared across K/V/Q projections) ----------------
  bf16x8 xv[4][4];
#pragma unroll
  for (int kk = 0; kk < 4; ++kk)
#pragma unroll
    for (int tt = 0; tt < 4; ++tt) {
      int tok = tt * 16 + lr; if (tok > 48) tok = 48;
      xv[kk][tt] = *reinterpret_cast<const bf16x8*>(&lds[tok * 136 + kk * 32 + kg * 8]);
    }

  // ---------------- K projection: D[ch][tok] -> packed A-frags kf[ct][tt] ----------------
  bf16x8 kf[2][4];
  {
    bf16x8 wk[4][2];
#pragma unroll
    for (int kk = 0; kk < 4; ++kk)
#pragma unroll
      for (int ct = 0; ct < 2; ++ct)
        wk[kk][ct] = *reinterpret_cast<const bf16x8*>(&wW[16384 + (h * 32 + ct * 16 + lr) * 128 + kk * 32 + kg * 8]);
    f32x4 accK[2][4] = {};
#pragma unroll
    for (int kk = 0; kk < 4; ++kk)
#pragma unroll
      for (int ct = 0; ct < 2; ++ct)
#pragma unroll
        for (int tt = 0; tt < 4; ++tt)
          accK[ct][tt] = __builtin_amdgcn_mfma_f32_16x16x32_bf16(wk[kk][ct], xv[kk][tt], accK[ct][tt], 0, 0, 0);
    float4 bkv[2];
#pragma unroll
    for (int ct = 0; ct < 2; ++ct)
      bkv[ct] = *reinterpret_cast<const float4*>(&wB[128 + h * 32 + ct * 16 + kg * 4]);
#pragma unroll
    for (int ct = 0; ct < 2; ++ct)
#pragma unroll
      for (int tt = 0; tt < 4; ++tt)
        kf[ct][tt] = paddb(accK[ct][tt], bkv[ct]);
  }

  // ---------------- V projection: D[tok][ch] -> packed A-frags vf[tt][nt] ----------------
  bf16x8 vf[4][2];
  {
    bf16x8 wvv[4][2];
#pragma unroll
    for (int kk = 0; kk < 4; ++kk)
#pragma unroll
      for (int nt = 0; nt < 2; ++nt)
        wvv[kk][nt] = *reinterpret_cast<const bf16x8*>(&wW[32768 + (h * 32 + nt * 16 + lr) * 128 + kk * 32 + kg * 8]);
    f32x4 accV[4][2] = {};
#pragma unroll
    for (int kk = 0; kk < 4; ++kk)
#pragma unroll
      for (int tt = 0; tt < 4; ++tt)
#pragma unroll
        for (int nt = 0; nt < 2; ++nt)
          accV[tt][nt] = __builtin_amdgcn_mfma_f32_16x16x32_bf16(xv[kk][tt], wvv[kk][nt], accV[tt][nt], 0, 0, 0);
    float bvs[2];
#pragma unroll
    for (int nt = 0; nt < 2; ++nt) bvs[nt] = wB[256 + h * 32 + nt * 16 + lr];
#pragma unroll
    for (int tt = 0; tt < 4; ++tt)
#pragma unroll
      for (int nt = 0; nt < 2; ++nt) {
        f32x4 t = accV[tt][nt];
        t[0] += bvs[nt]; t[1] += bvs[nt]; t[2] += bvs[nt]; t[3] += bvs[nt];
        vf[tt][nt] = padd(t);
      }
  }

  // ---------------- Q projection: D[ch][qt] -> packed B-frags qp[ct][bt] ----------------
  bf16x8 qp[2][4];
  {
    bf16x8 wq[4][2];
#pragma unroll
    for (int kk = 0; kk < 4; ++kk)
#pragma unroll
      for (int ct = 0; ct < 2; ++ct)
        wq[kk][ct] = *reinterpret_cast<const bf16x8*>(&wW[(h * 32 + ct * 16 + lr) * 128 + kk * 32 + kg * 8]);
    f32x4 accQ[2][4] = {};
#pragma unroll
    for (int kk = 0; kk < 4; ++kk)
#pragma unroll
      for (int ct = 0; ct < 2; ++ct)
#pragma unroll
        for (int bt = 0; bt < 4; ++bt)
          accQ[ct][bt] = __builtin_amdgcn_mfma_f32_16x16x32_bf16(wq[kk][ct], xv[kk][bt], accQ[ct][bt], 0, 0, 0);
    float4 bqv[2];
#pragma unroll
    for (int ct = 0; ct < 2; ++ct)
      bqv[ct] = *reinterpret_cast<const float4*>(&wB[h * 32 + ct * 16 + kg * 4]);
#pragma unroll
    for (int ct = 0; ct < 2; ++ct)
#pragma unroll
      for (int bt = 0; bt < 4; ++bt)
        qp[ct][bt] = paddb(accQ[ct][bt], bqv[ct]);
  }

  // ---------------- S^T[kt][qt] (all heads' kt x this head's full qt range) ----------------
  const int cls = ((wi == 15) ? 2 : 0) + ((wj == 15) ? 1 : 0);
  f32x4 s[4][4] = {};  // [tt kt-tile][bt qt-tile]
#pragma unroll
  for (int tt = 0; tt < 4; ++tt)
#pragma unroll
    for (int bt = 0; bt < 4; ++bt) {
      s[tt][bt] = __builtin_amdgcn_mfma_f32_16x16x32_bf16(kf[0][tt], qp[0][bt], s[tt][bt], 0, 0, 0);
      s[tt][bt] = __builtin_amdgcn_mfma_f32_16x16x32_bf16(kf[1][tt], qp[1][bt], s[tt][bt], 0, 0, 0);
    }

  // ---------------- softmax per qt column + pack P ----------------
  float inv[4];
  bf16x8 pf[4][4];  // [tt kt-chunk][bt]
#pragma unroll
  for (int bt = 0; bt < 4; ++bt) {
    int qtb = bt * 16 + lr;
    const float* rp = wRM + (((size_t)cls * 4 + h) * 64 + qtb) * 64 + kg * 4;
    float4 r4[4];
#pragma unroll
    for (int tt = 0; tt < 4; ++tt)
      r4[tt] = *reinterpret_cast<const float4*>(&rp[tt * 16]);
    float mx = -3.0e38f;
#pragma unroll
    for (int tt = 0; tt < 4; ++tt) {
      s[tt][bt][0] += r4[tt].x; s[tt][bt][1] += r4[tt].y;
      s[tt][bt][2] += r4[tt].z; s[tt][bt][3] += r4[tt].w;
      mx = fmaxf(mx, fmaxf(fmaxf(s[tt][bt][0], s[tt][bt][1]), fmaxf(s[tt][bt][2], s[tt][bt][3])));
    }
    mx = fmaxf(mx, __shfl_xor(mx, 16));
    mx = fmaxf(mx, __shfl_xor(mx, 32));
    float sum = 0.0f;
#pragma unroll
    for (int tt = 0; tt < 4; ++tt) {
#pragma unroll
      for (int i = 0; i < 4; ++i) {
        float e = __expf(s[tt][bt][i] - mx);
        s[tt][bt][i] = e; sum += e;
      }
    }
    sum += __shfl_xor(sum, 16);
    sum += __shfl_xor(sum, 32);
    inv[bt] = 1.0f / sum;
#pragma unroll
    for (int tt = 0; tt < 4; ++tt)
      pf[tt][bt] = padd(s[tt][bt]);
  }

  // ---------------- O^T[d][qt] = V^T P^T ----------------
  f32x4 o[2][4] = {};  // [nt d-tile][bt]
#pragma unroll
  for (int nt = 0; nt < 2; ++nt)
#pragma unroll
    for (int bt = 0; bt < 4; ++bt)
#pragma unroll
      for (int tt = 0; tt < 4; ++tt)
        o[nt][bt] = __builtin_amdgcn_mfma_f32_16x16x32_bf16(vf[tt][nt], pf[tt][bt], o[nt][bt], 0, 0, 0);

  // ---------------- O (scaled) -> o_s[tok][ch] ----------------
#pragma unroll
  for (int bt = 0; bt < 4; ++bt) {
    int qtb = bt * 16 + lr;
    if (qtb < 49) {
      float iv = inv[bt];
#pragma unroll
      for (int nt = 0; nt < 2; ++nt) {
        ushort4 h4 = { f2bf(o[nt][bt][0] * iv), f2bf(o[nt][bt][1] * iv),
                       f2bf(o[nt][bt][2] * iv), f2bf(o[nt][bt][3] * iv) };
        *reinterpret_cast<ushort4*>(&lds[OS + qtb * 136 + h * 32 + nt * 16 + kg * 4]) = h4;
      }
    }
  }
  // proj weights issued before the barrier (independent of o_s)
  const int c0 = wv * 32;
  bf16x8 eaw[4][2];
  {
    const ushort* W = wW + 3 * 16384;
#pragma unroll
    for (int kk = 0; kk < 4; ++kk)
#pragma unroll
      for (int mt = 0; mt < 2; ++mt)
        eaw[kk][mt] = *reinterpret_cast<const bf16x8*>(&W[(c0 + mt * 16 + lr) * 128 + kk * 32 + kg * 8]);
  }
  __syncthreads();  // barrier 2

  // ---------------- output projection (swapped) + float4 scatter ----------------
  {
    bf16x8 bo[4][4];
#pragma unroll
    for (int kk = 0; kk < 4; ++kk)
#pragma unroll
      for (int ntk = 0; ntk < 4; ++ntk) {
        int tok = ntk * 16 + lr; if (tok > 48) tok = 48;
        bo[kk][ntk] = *reinterpret_cast<const bf16x8*>(&lds[OS + tok * 136 + kk * 32 + kg * 8]);
      }
    f32x4 acc[2][4] = {};
#pragma unroll
    for (int kk = 0; kk < 4; ++kk)
#pragma unroll
      for (int mt = 0; mt < 2; ++mt)
#pragma unroll
        for (int ntk = 0; ntk < 4; ++ntk)
          acc[mt][ntk] = __builtin_amdgcn_mfma_f32_16x16x32_bf16(eaw[kk][mt], bo[kk][ntk], acc[mt][ntk], 0, 0, 0);
#pragma unroll
    for (int mt = 0; mt < 2; ++mt) {
      float4 b4 = *reinterpret_cast<const float4*>(&wB[384 + c0 + mt * 16 + kg * 4]);
#pragma unroll
      for (int ntk = 0; ntk < 4; ++ntk) {
        int tok = ntk * 16 + lr;
        if (tok < 49) {
          int r = d7(tok), c = tok - r * 7;
          int gh = wi * 7 + r + SHF; if (gh >= IMG) gh -= IMG;
          int gw = wj * 7 + c + SHF; if (gw >= IMG) gw -= IMG;
          float4 o4 = { acc[mt][ntk][0] + b4.x, acc[mt][ntk][1] + b4.y,
                        acc[mt][ntk][2] + b4.z, acc[mt][ntk][3] + b4.w };
          *reinterpret_cast<float4*>(out + gBase + ((size_t)gh * IMG + gw) * 128 + c0 + mt * 16 + kg * 4) = o4;
        }
      }
    }
  }
}

extern "C" void kernel_launch(void* const* d_in, const int* in_sizes, int n_in,
                              void* d_out, int out_size, void* d_ws, size_t ws_size,
                              hipStream_t stream) {
  const float* X = (const float*)d_in[0];
  const float* Wq = (const float*)d_in[3];
  const float* Wk = (const float*)d_in[4];
  const float* Wv = (const float*)d_in[5];
  const float* Wp = (const float*)d_in[6];
  const float* bq = (const float*)d_in[7];
  const float* bk = (const float*)d_in[8];
  const float* bv = (const float*)d_in[9];
  const float* bp = (const float*)d_in[10];
  const float* tbl = (const float*)d_in[11];

  ushort* wW = (ushort*)d_ws;                             // 4 x [128][128] bf16 = 131072 B
  float* wB = (float*)((char*)d_ws + 131072);             // 4 x [128] f32   = 2048 B
  float* wRM = (float*)((char*)d_ws + 131072 + 2048);     // [4][4][64][64] f32 = 262144 B

  prep_kernel<<<dim3(514), dim3(256), 0, stream>>>(Wq, Wk, Wv, Wp, bq, bk, bv, bp, tbl, wW, wB, wRM);
  swin_kernel<<<dim3(8192), dim3(256), 0, stream>>>(X, wW, wB, wRM, (float*)d_out);
}